// Round 8
// baseline (153.222 us; speedup 1.0000x reference)
//
#include <hip/hip_runtime.h>
#include <hip/hip_bf16.h>

#define NROWS 8192
#define DDIM 64
#define MARGIN_F 1.0f
#define EPS_F 1e-6f
#define NEG_BIG -1.0e30f

// ws layout (bytes):
//  Abf  [0, 1 MB)     bf16[8192][64] (a+eps)
//  Pbf  [1 MB, 2 MB)  bf16[8192][64]
//  base = 2 MB:
//   a2g     +0     float[8192]  |a+eps|^2 (fp32 exact)
//   pdg     +32K   float[8192]  pos_dist + margin (fp32 exact)
//   p2g     +64K   float[8192]  |p|^2
//   hdg     +96K   float[8192]  diag hinge per row (bf16-gram), to subtract
//   sel     +128K  int[8192]    sorted indices of labels==1
//   partial +160K  float[4096]  per-block sums
//   cnt     +176K  int
//   done    +176K+4 uint        last-block-done counter

typedef __attribute__((ext_vector_type(8))) short bf16x8;
typedef __attribute__((ext_vector_type(4))) float f32x4;

static __device__ __forceinline__ unsigned short f2bf(float x) {
    __hip_bfloat16 h = __float2bfloat16(x);
    return *reinterpret_cast<unsigned short*>(&h);
}
static __device__ __forceinline__ float bf2f(unsigned short u) {
    return __uint_as_float(((unsigned)u) << 16);
}

// Fused prep (blocks 0..511) + compaction (block 512). Zero contended atomics.
__global__ __launch_bounds__(256) void
prep_compact_kernel(const float* __restrict__ A, const float* __restrict__ P,
                    const int* __restrict__ labels,
                    unsigned short* __restrict__ Abf, unsigned short* __restrict__ Pbf,
                    float* __restrict__ a2g, float* __restrict__ pdg,
                    float* __restrict__ p2g, float* __restrict__ hdg,
                    int* __restrict__ sel, int* __restrict__ cnt,
                    unsigned int* __restrict__ done) {
    __shared__ int lab[256 * 33];   // only used by block 512
    __shared__ int scan[256];
    int t = threadIdx.x;

    if (blockIdx.x < 512) {
        // prep: 16 threads per row, 4 cols each
        int gid = blockIdx.x * 256 + t;
        int row = gid >> 4;
        int c4  = (gid & 15) * 4;
        float4 a = *(const float4*)&A[row * DDIM + c4];
        float4 p = *(const float4*)&P[row * DDIM + c4];
        a.x += EPS_F; a.y += EPS_F; a.z += EPS_F; a.w += EPS_F;
        ushort4 ab, pb;
        ab.x = f2bf(a.x); ab.y = f2bf(a.y); ab.z = f2bf(a.z); ab.w = f2bf(a.w);
        pb.x = f2bf(p.x); pb.y = f2bf(p.y); pb.z = f2bf(p.z); pb.w = f2bf(p.w);
        *(ushort4*)&Abf[row * DDIM + c4] = ab;
        *(ushort4*)&Pbf[row * DDIM + c4] = pb;
        float va2 = a.x*a.x + a.y*a.y + a.z*a.z + a.w*a.w;
        float vp2 = p.x*p.x + p.y*p.y + p.z*p.z + p.w*p.w;
        float vap = a.x*p.x + a.y*p.y + a.z*p.z + a.w*p.w;
        // bf16-rounded diag dot (matches what main's MFMA adds at (i,i))
        float vdd = bf2f(ab.x)*bf2f(pb.x) + bf2f(ab.y)*bf2f(pb.y)
                  + bf2f(ab.z)*bf2f(pb.z) + bf2f(ab.w)*bf2f(pb.w);
        #pragma unroll
        for (int off = 8; off; off >>= 1) {
            va2 += __shfl_xor(va2, off);
            vp2 += __shfl_xor(vp2, off);
            vap += __shfl_xor(vap, off);
            vdd += __shfl_xor(vdd, off);
        }
        if ((t & 15) == 0) {
            a2g[row] = va2;
            p2g[row] = vp2;
            float pd = sqrtf(fmaxf(va2 + vp2 - 2.0f * vap, 1e-12f)) + MARGIN_F;
            pdg[row] = pd;
            float sqd = fmaxf(va2 + vp2 - 2.0f * vdd, 1e-12f);
            hdg[row] = fmaxf(pd - __builtin_amdgcn_sqrtf(sqd), 0.0f);
        }
    } else {
        // compaction: deterministic, sorted, no atomics
        if (t == 0) *done = 0u;      // init for main's last-block protocol
        #pragma unroll
        for (int i = 0; i < 32; ++i) {
            int j = i * 256 + t;                 // coalesced global read
            lab[(j >> 5) * 33 + (j & 31)] = labels[j];
        }
        __syncthreads();
        int lc = 0;
        #pragma unroll
        for (int i = 0; i < 32; ++i) lc += (lab[t * 33 + i] == 1) ? 1 : 0;
        scan[t] = lc;
        __syncthreads();
        for (int off = 1; off < 256; off <<= 1) {
            int v = (t >= off) ? scan[t - off] : 0;
            __syncthreads();
            if (t >= off) scan[t] += v;
            __syncthreads();
        }
        int o = scan[t] - lc;
        for (int i = 0; i < 32; ++i) {
            if (lab[t * 33 + i] == 1) sel[o++] = t * 32 + i;
        }
        if (t == 255) *cnt = scan[255];
    }
}

// 128x128 tile per block (grid 64x64 = 4096 blocks -> deep per-CU queue for
// latency hiding; R7 showed per-block col-sweeps regress). Fragments direct
// from L2. Last-finishing block performs the final reduction (no 3rd dispatch).
__global__ __launch_bounds__(256) void
main_kernel(const unsigned short* __restrict__ Abf, const unsigned short* __restrict__ Pbf,
            const float* __restrict__ a2g, const float* __restrict__ pdg,
            const float* __restrict__ p2g, const float* __restrict__ hdg,
            const int* __restrict__ sel, const int* __restrict__ cnt,
            float* __restrict__ partial, unsigned int* __restrict__ done,
            float* __restrict__ out) {
    __shared__ float sA2[128], sPd[128];
    __shared__ int   sGi[128];
    __shared__ float wsum[4];
    __shared__ int   lastFlag;

    int M = *cnt;
    int t = threadIdx.x;
    int row0 = blockIdx.y << 7;
    int col0 = blockIdx.x << 7;
    int bid  = (blockIdx.y << 6) + blockIdx.x;

    int wid  = t >> 6;
    int lane = t & 63;

    if (row0 < M) {
        int wm   = (wid >> 1) << 6;
        int wn   = (wid & 1) << 6;
        int lm   = lane & 15;
        int quad = lane >> 4;

        // B fragments first (no dependence on sel): loads in flight across barrier.
        bf16x8 bg0[4], bg1[4];
        float spv[4];
        #pragma unroll
        for (int b = 0; b < 4; ++b) {
            int cj = col0 + wn + b * 16 + lm;
            const unsigned short* pb = Pbf + (size_t)cj * DDIM + quad * 8;
            bg0[b] = *(const bf16x8*)pb;
            bg1[b] = *(const bf16x8*)(pb + 32);
            spv[b] = p2g[cj];
        }

        if (t < 128) {
            int ri = row0 + t;
            int gi = sel[min(ri, M - 1)];
            sGi[t] = gi;
            sA2[t] = a2g[gi];
            sPd[t] = (ri < M) ? pdg[gi] : NEG_BIG;   // tail rows can't pass relu
        }
        __syncthreads();

        bf16x8 af0[4], af1[4];
        #pragma unroll
        for (int a = 0; a < 4; ++a) {
            const unsigned short* pa = Abf + (size_t)sGi[wm + a * 16 + lm] * DDIM + quad * 8;
            af0[a] = *(const bf16x8*)pa;
            af1[a] = *(const bf16x8*)(pa + 32);
        }

        f32x4 acc[4][4] = {};
        #pragma unroll
        for (int a = 0; a < 4; ++a)
            #pragma unroll
            for (int b = 0; b < 4; ++b)
                acc[a][b] = __builtin_amdgcn_mfma_f32_16x16x32_bf16(af0[a], bg0[b], acc[a][b], 0, 0, 0);
        #pragma unroll
        for (int a = 0; a < 4; ++a)
            #pragma unroll
            for (int b = 0; b < 4; ++b)
                acc[a][b] = __builtin_amdgcn_mfma_f32_16x16x32_bf16(af1[a], bg1[b], acc[a][b], 0, 0, 0);

        // Branchless epilogue; diagonal handled globally via hdg subtraction.
        // C/D layout: col = lane&15, row = quad*4 + reg.
        float bsum = 0.0f;
        #pragma unroll
        for (int a = 0; a < 4; ++a) {
            #pragma unroll
            for (int r = 0; r < 4; ++r) {
                int il = wm + a * 16 + quad * 4 + r;
                float ra2 = sA2[il];
                float rpd = sPd[il];
                #pragma unroll
                for (int b = 0; b < 4; ++b) {
                    float sq = fmaf(-2.0f, acc[a][b][r], ra2 + spv[b]);
                    float h  = rpd - __builtin_amdgcn_sqrtf(sq);
                    bsum += fmaxf(h, 0.0f);
                }
            }
        }

        #pragma unroll
        for (int off = 32; off; off >>= 1) bsum += __shfl_xor(bsum, off);
        if (lane == 0) wsum[wid] = bsum;
        __syncthreads();
    }

    // Publish partial, then last-finishing block reduces everything.
    if (t == 0) {
        float s = (row0 < M) ? (wsum[0] + wsum[1] + wsum[2] + wsum[3]) : 0.0f;
        partial[bid] = s;
        __threadfence();                         // device-scope release
        unsigned v = atomicAdd(done, 1u);
        lastFlag = (v == 4095u);
    }
    __syncthreads();
    if (!lastFlag) return;

    float s = 0.0f;
    #pragma unroll
    for (int i = 0; i < 16; ++i)
        s += atomicAdd(&partial[t + i * 256], 0.0f);   // coherent (L2) reads
    for (int i = t; i < M; i += 256)
        s -= hdg[sel[i]];                              // remove diagonals (prep data)
    #pragma unroll
    for (int off = 32; off; off >>= 1) s += __shfl_xor(s, off);
    if ((t & 63) == 0) wsum[wid] = s;
    __syncthreads();
    if (t == 0) {
        float tot = wsum[0] + wsum[1] + wsum[2] + wsum[3];
        out[0] = (M > 0) ? tot / ((float)M * (float)(NROWS - 1)) : 0.0f;
    }
}

extern "C" void kernel_launch(void* const* d_in, const int* in_sizes, int n_in,
                              void* d_out, int out_size, void* d_ws, size_t ws_size,
                              hipStream_t stream) {
    const float* A      = (const float*)d_in[0];
    const float* P      = (const float*)d_in[1];
    const int*   labels = (const int*)d_in[2];
    float* out = (float*)d_out;

    char* ws = (char*)d_ws;
    unsigned short* Abf = (unsigned short*)(ws);
    unsigned short* Pbf = (unsigned short*)(ws + (1 << 20));
    char* base = ws + (2 << 20);
    float* a2g     = (float*)(base);
    float* pdg     = (float*)(base + 32768);
    float* p2g     = (float*)(base + 65536);
    float* hdg     = (float*)(base + 98304);
    int*   sel     = (int*)(base + 131072);
    float* partial = (float*)(base + 163840);
    int*   cnt     = (int*)(base + 180224);
    unsigned int* done = (unsigned int*)(base + 180228);

    prep_compact_kernel<<<dim3(513), dim3(256), 0, stream>>>(A, P, labels, Abf, Pbf,
                                                             a2g, pdg, p2g, hdg, sel,
                                                             cnt, done);

    main_kernel<<<dim3(64, 64), dim3(256), 0, stream>>>(Abf, Pbf, a2g, pdg, p2g, hdg,
                                                        sel, cnt, partial, done, out);
}

// Round 9
// 92.810 us; speedup vs baseline: 1.6509x; 1.6509x over previous
//
#include <hip/hip_runtime.h>
#include <hip/hip_bf16.h>

#define NROWS 8192
#define DDIM 64
#define MARGIN_F 1.0f
#define EPS_F 1e-6f
#define NEG_BIG -1.0e30f

// ws layout (bytes):
//  Abf  [0, 1 MB)     bf16[8192][64] (a+eps)
//  Pbf  [1 MB, 2 MB)  bf16[8192][64]
//  base = 2 MB:
//   a2g      +0     float[8192]  |a+eps|^2 (fp32 exact)
//   pdg      +32K   float[8192]  pos_dist + margin (fp32 exact)
//   p2g      +64K   float[8192]  |p|^2
//   hdg      +96K   float[8192]  diag hinge per row (bf16-gram), to subtract
//   sel      +128K  int[8192]    sorted indices of labels==1
//   partial4 +160K  float[16384] per-WAVE sums (4096 blocks x 4 waves)
//   cnt      +224K  int

typedef __attribute__((ext_vector_type(8))) short bf16x8;
typedef __attribute__((ext_vector_type(4))) float f32x4;

static __device__ __forceinline__ unsigned short f2bf(float x) {
    __hip_bfloat16 h = __float2bfloat16(x);
    return *reinterpret_cast<unsigned short*>(&h);
}
static __device__ __forceinline__ float bf2f(unsigned short u) {
    return __uint_as_float(((unsigned)u) << 16);
}

// Fused prep (blocks 0..511) + compaction (block 512). Zero contended atomics.
__global__ __launch_bounds__(256) void
prep_compact_kernel(const float* __restrict__ A, const float* __restrict__ P,
                    const int* __restrict__ labels,
                    unsigned short* __restrict__ Abf, unsigned short* __restrict__ Pbf,
                    float* __restrict__ a2g, float* __restrict__ pdg,
                    float* __restrict__ p2g, float* __restrict__ hdg,
                    int* __restrict__ sel, int* __restrict__ cnt) {
    __shared__ int lab[256 * 33];   // only used by block 512
    __shared__ int scan[256];
    int t = threadIdx.x;

    if (blockIdx.x < 512) {
        // prep: 16 threads per row, 4 cols each
        int gid = blockIdx.x * 256 + t;
        int row = gid >> 4;
        int c4  = (gid & 15) * 4;
        float4 a = *(const float4*)&A[row * DDIM + c4];
        float4 p = *(const float4*)&P[row * DDIM + c4];
        a.x += EPS_F; a.y += EPS_F; a.z += EPS_F; a.w += EPS_F;
        ushort4 ab, pb;
        ab.x = f2bf(a.x); ab.y = f2bf(a.y); ab.z = f2bf(a.z); ab.w = f2bf(a.w);
        pb.x = f2bf(p.x); pb.y = f2bf(p.y); pb.z = f2bf(p.z); pb.w = f2bf(p.w);
        *(ushort4*)&Abf[row * DDIM + c4] = ab;
        *(ushort4*)&Pbf[row * DDIM + c4] = pb;
        float va2 = a.x*a.x + a.y*a.y + a.z*a.z + a.w*a.w;
        float vp2 = p.x*p.x + p.y*p.y + p.z*p.z + p.w*p.w;
        float vap = a.x*p.x + a.y*p.y + a.z*p.z + a.w*p.w;
        // bf16-rounded diag dot (matches what main's MFMA adds at (i,i))
        float vdd = bf2f(ab.x)*bf2f(pb.x) + bf2f(ab.y)*bf2f(pb.y)
                  + bf2f(ab.z)*bf2f(pb.z) + bf2f(ab.w)*bf2f(pb.w);
        #pragma unroll
        for (int off = 8; off; off >>= 1) {
            va2 += __shfl_xor(va2, off);
            vp2 += __shfl_xor(vp2, off);
            vap += __shfl_xor(vap, off);
            vdd += __shfl_xor(vdd, off);
        }
        if ((t & 15) == 0) {
            a2g[row] = va2;
            p2g[row] = vp2;
            float pd = sqrtf(fmaxf(va2 + vp2 - 2.0f * vap, 1e-12f)) + MARGIN_F;
            pdg[row] = pd;
            float sqd = fmaxf(va2 + vp2 - 2.0f * vdd, 1e-12f);
            hdg[row] = fmaxf(pd - __builtin_amdgcn_sqrtf(sqd), 0.0f);
        }
    } else {
        // compaction: deterministic, sorted, no atomics
        #pragma unroll
        for (int i = 0; i < 32; ++i) {
            int j = i * 256 + t;                 // coalesced global read
            lab[(j >> 5) * 33 + (j & 31)] = labels[j];
        }
        __syncthreads();
        int lc = 0;
        #pragma unroll
        for (int i = 0; i < 32; ++i) lc += (lab[t * 33 + i] == 1) ? 1 : 0;
        scan[t] = lc;
        __syncthreads();
        for (int off = 1; off < 256; off <<= 1) {
            int v = (t >= off) ? scan[t - off] : 0;
            __syncthreads();
            if (t >= off) scan[t] += v;
            __syncthreads();
        }
        int o = scan[t] - lc;
        for (int i = 0; i < 32; ++i) {
            if (lab[t * 33 + i] == 1) sel[o++] = t * 32 + i;
        }
        if (t == 255) *cnt = scan[255];
    }
}

// 128x128 tile per block (4096 blocks). NO LDS, NO barriers: wave-local meta
// + __shfl broadcasts; per-WAVE partial stores. Fragments direct from L2.
__global__ __launch_bounds__(256) void
main_kernel(const unsigned short* __restrict__ Abf, const unsigned short* __restrict__ Pbf,
            const float* __restrict__ a2g, const float* __restrict__ pdg,
            const float* __restrict__ p2g, const int* __restrict__ sel,
            const int* __restrict__ cnt, float* __restrict__ partial4) {
    int M = *cnt;
    int t = threadIdx.x;
    int wid  = t >> 6;
    int lane = t & 63;
    int row0 = blockIdx.y << 7;
    int col0 = blockIdx.x << 7;
    int slot = (((blockIdx.y << 6) + blockIdx.x) << 2) + wid;

    if (row0 >= M) { if (lane == 0) partial4[slot] = 0.0f; return; }

    int wm   = (wid >> 1) << 6;
    int wn   = (wid & 1) << 6;
    int lm   = lane & 15;
    int quad = lane >> 4;

    // B fragments + col meta: independent loads, issue first.
    bf16x8 bg0[4], bg1[4];
    float spv[4];
    #pragma unroll
    for (int b = 0; b < 4; ++b) {
        int cj = col0 + wn + b * 16 + lm;
        const unsigned short* pb = Pbf + (size_t)cj * DDIM + quad * 8;
        bg0[b] = *(const bf16x8*)pb;
        bg1[b] = *(const bf16x8*)(pb + 32);
        spv[b] = p2g[cj];
    }

    // Wave-local row meta: lane L owns wave-row L. One coalesced load each.
    int Lrow  = row0 + wm + lane;
    int gi    = sel[min(Lrow, M - 1)];
    float myA2 = a2g[gi];
    float myPd = (Lrow < M) ? pdg[gi] : NEG_BIG;   // tail rows can't pass relu

    // A fragments via __shfl row-index broadcast (no LDS, no barrier).
    bf16x8 af0[4], af1[4];
    #pragma unroll
    for (int a = 0; a < 4; ++a) {
        int gia = __shfl(gi, a * 16 + lm);
        const unsigned short* pa = Abf + (size_t)gia * DDIM + quad * 8;
        af0[a] = *(const bf16x8*)pa;
        af1[a] = *(const bf16x8*)(pa + 32);
    }

    f32x4 acc[4][4] = {};
    #pragma unroll
    for (int a = 0; a < 4; ++a)
        #pragma unroll
        for (int b = 0; b < 4; ++b)
            acc[a][b] = __builtin_amdgcn_mfma_f32_16x16x32_bf16(af0[a], bg0[b], acc[a][b], 0, 0, 0);
    #pragma unroll
    for (int a = 0; a < 4; ++a)
        #pragma unroll
        for (int b = 0; b < 4; ++b)
            acc[a][b] = __builtin_amdgcn_mfma_f32_16x16x32_bf16(af1[a], bg1[b], acc[a][b], 0, 0, 0);

    // Branchless epilogue; diagonal handled globally via hdg subtraction.
    // C/D layout: col = lane&15, row = quad*4 + reg. Row meta via __shfl.
    float bsum = 0.0f;
    #pragma unroll
    for (int a = 0; a < 4; ++a) {
        #pragma unroll
        for (int r = 0; r < 4; ++r) {
            int src = a * 16 + quad * 4 + r;
            float ra2 = __shfl(myA2, src);
            float rpd = __shfl(myPd, src);
            #pragma unroll
            for (int b = 0; b < 4; ++b) {
                float sq = fmaf(-2.0f, acc[a][b][r], ra2 + spv[b]);
                float h  = rpd - __builtin_amdgcn_sqrtf(sq);
                bsum += fmaxf(h, 0.0f);
            }
        }
    }

    #pragma unroll
    for (int off = 32; off; off >>= 1) bsum += __shfl_xor(bsum, off);
    if (lane == 0) partial4[slot] = bsum;
}

__global__ __launch_bounds__(256) void
finalize_kernel(const int* __restrict__ cnt, const float* __restrict__ partial4,
                const float* __restrict__ hdg, const int* __restrict__ sel,
                float* __restrict__ out) {
    __shared__ float wsum[4];
    int t = threadIdx.x;
    const float4* p4 = (const float4*)partial4;
    float s = 0.0f;
    #pragma unroll
    for (int i = 0; i < 16; ++i) {
        float4 v = p4[i * 256 + t];
        s += v.x + v.y + v.z + v.w;
    }
    int M = *cnt;
    for (int i = t; i < M; i += 256) s -= hdg[sel[i]];   // remove diagonals
    #pragma unroll
    for (int off = 32; off; off >>= 1) s += __shfl_xor(s, off);
    if ((t & 63) == 0) wsum[t >> 6] = s;
    __syncthreads();
    if (t == 0) {
        float tot = wsum[0] + wsum[1] + wsum[2] + wsum[3];
        out[0] = (M > 0) ? tot / ((float)M * (float)(NROWS - 1)) : 0.0f;
    }
}

extern "C" void kernel_launch(void* const* d_in, const int* in_sizes, int n_in,
                              void* d_out, int out_size, void* d_ws, size_t ws_size,
                              hipStream_t stream) {
    const float* A      = (const float*)d_in[0];
    const float* P      = (const float*)d_in[1];
    const int*   labels = (const int*)d_in[2];
    float* out = (float*)d_out;

    char* ws = (char*)d_ws;
    unsigned short* Abf = (unsigned short*)(ws);
    unsigned short* Pbf = (unsigned short*)(ws + (1 << 20));
    char* base = ws + (2 << 20);
    float* a2g      = (float*)(base);
    float* pdg      = (float*)(base + 32768);
    float* p2g      = (float*)(base + 65536);
    float* hdg      = (float*)(base + 98304);
    int*   sel      = (int*)(base + 131072);
    float* partial4 = (float*)(base + 163840);
    int*   cnt      = (int*)(base + 229376);

    prep_compact_kernel<<<dim3(513), dim3(256), 0, stream>>>(A, P, labels, Abf, Pbf,
                                                             a2g, pdg, p2g, hdg, sel, cnt);

    main_kernel<<<dim3(64, 64), dim3(256), 0, stream>>>(Abf, Pbf, a2g, pdg, p2g,
                                                        sel, cnt, partial4);

    finalize_kernel<<<1, dim3(256), 0, stream>>>(cnt, partial4, hdg, sel, out);
}